// Round 3
// baseline (536.413 us; speedup 1.0000x reference)
//
#include <hip/hip_runtime.h>
#include <hip/hip_bf16.h>

typedef __hip_bfloat16 bf16;
typedef __attribute__((ext_vector_type(8))) short short8;
typedef __attribute__((ext_vector_type(4))) short short4v;
typedef __attribute__((ext_vector_type(4))) float f32x4;

#define DIMC 2048
#define TSEQ 2048
#define NB 2
#define KVH 4
#define NH 16
#define HD 128
#define KVD 512
#define SCALE 0.08838834764831845f

// D = A(16x32) * B(32x16) + D, bf16 in, f32 out. Builtin so the compiler
// inserts the mandatory VALU-write -> MFMA-read wait states (inline asm
// skipped them -> stale SrcC reads -> NaN).
__device__ __forceinline__ void mfma16(f32x4& acc, short8 a, short8 b) {
  acc = __builtin_amdgcn_mfma_f32_16x16x32_bf16(a, b, acc, 0, 0, 0);
}

__device__ __forceinline__ void gload_lds16(const bf16* g, bf16* l) {
  __builtin_amdgcn_global_load_lds(
      (const __attribute__((address_space(1))) void*)g,
      (__attribute__((address_space(3))) void*)l, 16, 0, 0);
}

// ---------------- x: fp32 -> bf16, vectorized ----------------
__global__ __launch_bounds__(256) void f2b(const float* __restrict__ in,
                                           bf16* __restrict__ out, long n4) {
  long i = (long)blockIdx.x * 256 + threadIdx.x;
  if (i >= n4) return;
  const f32x4 v = *(const f32x4*)(in + i * 4);
  union { short4v s; bf16 h[4]; } u;
#pragma unroll
  for (int j = 0; j < 4; ++j) u.h[j] = __float2bfloat16(v[j]);
  *(short4v*)(out + i * 4) = u.s;
}

// -------- transpose weights: fp32 W[2048][C] -> bf16 Wt[C][2048] --------
__global__ __launch_bounds__(256) void transpose_w_f2b(const float* __restrict__ in,
                                                       bf16* __restrict__ out, int C) {
  __shared__ bf16 tile[64][72];
  int rb = blockIdx.y * 64, cb = blockIdx.x * 64;
  int tx = threadIdx.x & 63, ty = threadIdx.x >> 6;
  for (int i = ty; i < 64; i += 4)
    tile[i][tx] = __float2bfloat16(in[(long)(rb + i) * C + cb + tx]);
  __syncthreads();
  for (int i = ty; i < 64; i += 4)
    out[(long)(cb + i) * DIMC + rb + tx] = tile[tx][i];
}

// ------------- GEMM: C[M][N] = A[M][K] * Bt[N][K]^T  (bf16 in) -------------
// m97 structure: 128x128 tile, BK=32, 4 waves each 64x64, global_load_lds w16.
// EPI: 0 = bf16 C[M][N]; 1 = bf16 scatter to vT[(b*4+kv)][d][t]; 2 = fp32 C.
template <int EPI>
__global__ __launch_bounds__(256) void gemm_bt(const bf16* __restrict__ A,
                                               const bf16* __restrict__ Bt,
                                               void* __restrict__ Cv,
                                               int M, int N, int K) {
  __shared__ bf16 As[128 * 32];
  __shared__ bf16 Bs[128 * 32];
  const int tid = threadIdx.x;
  const int lane = tid & 63, wid = tid >> 6;
  const long m0 = blockIdx.y * 128, n0 = blockIdx.x * 128;
  const int wm = (wid >> 1) * 64, wn = (wid & 1) * 64;
  f32x4 acc[4][4] = {};
  const int srow = lane >> 2, scol = (lane & 3) * 8;
  const bf16* Ag = A + (m0 + srow) * (long)K + scol;
  const bf16* Bg = Bt + (n0 + srow) * (long)K + scol;

  for (int k0 = 0; k0 < K; k0 += 32) {
    for (int p = 0; p < 2; ++p) {
      int rr = p * 64 + wid * 16;
      gload_lds16(Ag + (long)rr * K + k0, As + rr * 32);
      gload_lds16(Bg + (long)rr * K + k0, Bs + rr * 32);
    }
    __syncthreads();
    const int ko = (lane >> 4) * 8;
    short8 af[4], bq[4];
#pragma unroll
    for (int i = 0; i < 4; ++i) {
      af[i] = *(const short8*)(As + (wm + i * 16 + (lane & 15)) * 32 + ko);
      bq[i] = *(const short8*)(Bs + (wn + i * 16 + (lane & 15)) * 32 + ko);
    }
#pragma unroll
    for (int i = 0; i < 4; ++i)
#pragma unroll
      for (int j = 0; j < 4; ++j)
        mfma16(acc[i][j], af[i], bq[j]);
    __syncthreads();
  }
  const int cr = (lane >> 4) * 4, cc = lane & 15;
#pragma unroll
  for (int i = 0; i < 4; ++i)
#pragma unroll
    for (int j = 0; j < 4; ++j)
#pragma unroll
      for (int r = 0; r < 4; ++r) {
        long m = m0 + wm + i * 16 + cr + r;
        long n = n0 + wn + j * 16 + cc;
        float val = acc[i][j][r];
        if (EPI == 0) {
          ((bf16*)Cv)[m * N + n] = __float2bfloat16(val);
        } else if (EPI == 1) {
          // v projection elem (m = b*2048+t, n = kv*128+d) -> vT[b*4+kv][d][t]
          long z = (m >> 11) * 4 + (n >> 7);
          ((bf16*)Cv)[z * (HD * (long)TSEQ) + (n & 127) * (long)TSEQ + (m & 2047)] =
              __float2bfloat16(val);
        } else {
          ((float*)Cv)[m * N + n] = val;
        }
      }
}

// ---------------- flash attention fwd, full (non-causal) ----------------
// grid: (T/64, 16 heads, B). 4 waves; wave owns 16 q-rows. K/V tiles = 64.
__global__ __launch_bounds__(256) void attn_fwd(const bf16* __restrict__ Qp,
                                                const bf16* __restrict__ Kp,
                                                const bf16* __restrict__ Vt,
                                                bf16* __restrict__ AO) {
  __shared__ bf16 Ks[64 * 136];    // [s][d], pad 136
  __shared__ bf16 Vts[128 * 72];   // [d][s], pad 72
  __shared__ bf16 Plds[4][16 * 72];
  const int tid = threadIdx.x;
  const int lane = tid & 63, wid = tid >> 6;
  const int h = blockIdx.y, b = blockIdx.z;
  const int kv = h >> 2;
  const int t0 = blockIdx.x * 64;
  const int lr = lane & 15, lg = lane >> 4;

  short8 aq[4];
  {
    const bf16* qrow =
        Qp + ((long)(b * TSEQ + t0 + wid * 16 + lr)) * DIMC + h * HD + lg * 8;
#pragma unroll
    for (int c = 0; c < 4; ++c) aq[c] = *(const short8*)(qrow + c * 32);
  }
  f32x4 o[8] = {};
  float mrun[4], lrun[4];
#pragma unroll
  for (int r = 0; r < 4; ++r) { mrun[r] = -1e30f; lrun[r] = 0.f; }

  const bf16* Kg = Kp + (long)b * TSEQ * KVD + kv * HD;
  const bf16* Vg = Vt + ((long)(b * KVH + kv)) * HD * TSEQ;

  for (int s0 = 0; s0 < TSEQ; s0 += 64) {
#pragma unroll
    for (int p = 0; p < 4; ++p) {
      int e = tid * 8 + p * 2048;
      int kr = e >> 7, kc = e & 127;
      *(short8*)(Ks + kr * 136 + kc) =
          *(const short8*)(Kg + (long)(s0 + kr) * KVD + kc);
      int vd = e >> 6, vs = e & 63;
      *(short8*)(Vts + vd * 72 + vs) =
          *(const short8*)(Vg + (long)vd * TSEQ + s0 + vs);
    }
    __syncthreads();

    // S = Q K^T
    f32x4 sacc[4] = {};
#pragma unroll
    for (int sf = 0; sf < 4; ++sf)
#pragma unroll
      for (int c = 0; c < 4; ++c) {
        short8 kf = *(const short8*)(Ks + (sf * 16 + lr) * 136 + c * 32 + lg * 8);
        mfma16(sacc[sf], aq[c], kf);
      }

    // online softmax; lane holds rows lg*4+r, col sf*16+lr
    float sv[4][4], tmax[4];
#pragma unroll
    for (int r = 0; r < 4; ++r) tmax[r] = -1e30f;
#pragma unroll
    for (int sf = 0; sf < 4; ++sf)
#pragma unroll
      for (int r = 0; r < 4; ++r) {
        float v = sacc[sf][r] * SCALE;
        sv[sf][r] = v;
        tmax[r] = fmaxf(tmax[r], v);
      }
#pragma unroll
    for (int r = 0; r < 4; ++r) {
#pragma unroll
      for (int mm = 1; mm < 16; mm <<= 1)
        tmax[r] = fmaxf(tmax[r], __shfl_xor(tmax[r], mm));
      float mnew = fmaxf(mrun[r], tmax[r]);
      float fac = __expf(mrun[r] - mnew);
      mrun[r] = mnew;
      lrun[r] *= fac;
#pragma unroll
      for (int df = 0; df < 8; ++df) o[df][r] *= fac;
    }
    float psum[4] = {0.f, 0.f, 0.f, 0.f};
    bf16* Pw = Plds[wid];
#pragma unroll
    for (int sf = 0; sf < 4; ++sf)
#pragma unroll
      for (int r = 0; r < 4; ++r) {
        float p = __expf(sv[sf][r] - mrun[r]);
        psum[r] += p;
        Pw[(lg * 4 + r) * 72 + sf * 16 + lr] = __float2bfloat16(p);
      }
#pragma unroll
    for (int r = 0; r < 4; ++r) {
#pragma unroll
      for (int mm = 1; mm < 16; mm <<= 1)
        psum[r] += __shfl_xor(psum[r], mm);
      lrun[r] += psum[r];
    }

    // O += P V
#pragma unroll
    for (int c2 = 0; c2 < 2; ++c2) {
      short8 pa = *(const short8*)(Pw + lr * 72 + c2 * 32 + lg * 8);
#pragma unroll
      for (int df = 0; df < 8; ++df) {
        short8 vf = *(const short8*)(Vts + (df * 16 + lr) * 72 + c2 * 32 + lg * 8);
        mfma16(o[df], pa, vf);
      }
    }
    __syncthreads();
  }

  bf16* orow =
      AO + ((long)(b * TSEQ + t0 + wid * 16 + lg * 4)) * DIMC + h * HD + lr;
#pragma unroll
  for (int df = 0; df < 8; ++df)
#pragma unroll
    for (int r = 0; r < 4; ++r) {
      float v = o[df][r] / lrun[r];
      orow[(long)r * DIMC + df * 16] = __float2bfloat16(v);
    }
}

extern "C" void kernel_launch(void* const* d_in, const int* in_sizes, int n_in,
                              void* d_out, int out_size, void* d_ws, size_t ws_size,
                              hipStream_t stream) {
  const float* x  = (const float*)d_in[0];
  const float* Wq = (const float*)d_in[1];
  const float* Wk = (const float*)d_in[2];
  const float* Wv = (const float*)d_in[3];
  const float* Wo = (const float*)d_in[4];
  float* out = (float*)d_out;
  bf16* ws = (bf16*)d_ws;

  // ws layout (bf16 elems), with sequential reuse:
  bf16* xb  = ws;                 // [4096][2048] x (bf16); later reused as ao
  bf16* WT1 = xb + 8388608;       // [2048][2048] WqT, then WoT
  bf16* WT2 = WT1 + 4194304;      // [512][2048]  WkT, then WvT
  bf16* qp  = WT2 + 1048576;      // [4096][2048]
  bf16* kp  = qp + 8388608;       // [4096][512]
  bf16* vT  = kp + 2097152;       // [8][128][2048]
  // total: 50 MiB

  f2b<<<8192, 256, 0, stream>>>(x, xb, 2097152);
  transpose_w_f2b<<<dim3(32, 32), 256, 0, stream>>>(Wq, WT1, 2048);
  transpose_w_f2b<<<dim3(8, 32), 256, 0, stream>>>(Wk, WT2, 512);

  gemm_bt<0><<<dim3(16, 32), 256, 0, stream>>>(xb, WT1, qp, 4096, 2048, 2048);
  gemm_bt<0><<<dim3(4, 32), 256, 0, stream>>>(xb, WT2, kp, 4096, 512, 2048);

  transpose_w_f2b<<<dim3(8, 32), 256, 0, stream>>>(Wv, WT2, 512);    // reuse WT2
  gemm_bt<1><<<dim3(4, 32), 256, 0, stream>>>(xb, WT2, vT, 4096, 512, 2048);

  transpose_w_f2b<<<dim3(32, 32), 256, 0, stream>>>(Wo, WT1, 2048);  // reuse WT1

  bf16* ao = xb;  // x dead after V gemm
  attn_fwd<<<dim3(32, 16, 2), 256, 0, stream>>>(qp, kp, vT, ao);

  gemm_bt<2><<<dim3(16, 32), 256, 0, stream>>>(ao, WT1, out, 4096, 2048, 2048);
}

// Round 4
// 377.820 us; speedup vs baseline: 1.4198x; 1.4198x over previous
//
#include <hip/hip_runtime.h>
#include <hip/hip_bf16.h>

typedef __hip_bfloat16 bf16;
typedef __attribute__((ext_vector_type(8))) short short8;
typedef __attribute__((ext_vector_type(4))) short short4v;
typedef __attribute__((ext_vector_type(4))) float f32x4;

#define DIMC 2048
#define TSEQ 2048
#define NB 2
#define KVH 4
#define NH 16
#define HD 128
#define KVD 512
// softmax scale folded into Wq, in log2 domain: 1/sqrt(128) * log2(e)
#define QSCALE 0.12751744f

__device__ __forceinline__ void mfma16(f32x4& acc, short8 a, short8 b) {
  acc = __builtin_amdgcn_mfma_f32_16x16x32_bf16(a, b, acc, 0, 0, 0);
}

__device__ __forceinline__ void gload_lds16(const bf16* g, bf16* l) {
  __builtin_amdgcn_global_load_lds(
      (const __attribute__((address_space(1))) void*)g,
      (__attribute__((address_space(3))) void*)l, 16, 0, 0);
}

// ---------------- x: fp32 -> bf16, vectorized ----------------
__global__ __launch_bounds__(256) void f2b(const float* __restrict__ in,
                                           bf16* __restrict__ out, long n4) {
  long i = (long)blockIdx.x * 256 + threadIdx.x;
  if (i >= n4) return;
  const f32x4 v = *(const f32x4*)(in + i * 4);
  union { short4v s; bf16 h[4]; } u;
#pragma unroll
  for (int j = 0; j < 4; ++j) u.h[j] = __float2bfloat16(v[j]);
  *(short4v*)(out + i * 4) = u.s;
}

// ---- transpose weights: fp32 W[2048][C] -> bf16 Wt[C][2048], scaled ----
__global__ __launch_bounds__(256) void transpose_w_f2b(const float* __restrict__ in,
                                                       bf16* __restrict__ out, int C,
                                                       float scale) {
  __shared__ bf16 tile[64][72];
  int rb = blockIdx.y * 64, cb = blockIdx.x * 64;
  int tx = threadIdx.x & 63, ty = threadIdx.x >> 6;
  for (int i = ty; i < 64; i += 4)
    tile[i][tx] = __float2bfloat16(in[(long)(rb + i) * C + cb + tx] * scale);
  __syncthreads();
  for (int i = ty; i < 64; i += 4)
    out[(long)(cb + i) * DIMC + rb + tx] = tile[tx][i];
}

// ------------- GEMM: C[M][N] = A[M][K] * Bt[N][K]^T  (bf16 in) -------------
// EPI: 0 = bf16 C[M][N]; 1 = bf16 scatter to vT[(b*4+kv)][d][t]; 2 = fp32 C.
template <int EPI>
__global__ __launch_bounds__(256) void gemm_bt(const bf16* __restrict__ A,
                                               const bf16* __restrict__ Bt,
                                               void* __restrict__ Cv,
                                               int M, int N, int K) {
  __shared__ bf16 As[128 * 32];
  __shared__ bf16 Bs[128 * 32];
  const int tid = threadIdx.x;
  const int lane = tid & 63, wid = tid >> 6;
  const long m0 = blockIdx.y * 128, n0 = blockIdx.x * 128;
  const int wm = (wid >> 1) * 64, wn = (wid & 1) * 64;
  f32x4 acc[4][4] = {};
  const int srow = lane >> 2, scol = (lane & 3) * 8;
  const bf16* Ag = A + (m0 + srow) * (long)K + scol;
  const bf16* Bg = Bt + (n0 + srow) * (long)K + scol;

  for (int k0 = 0; k0 < K; k0 += 32) {
    for (int p = 0; p < 2; ++p) {
      int rr = p * 64 + wid * 16;
      gload_lds16(Ag + (long)rr * K + k0, As + rr * 32);
      gload_lds16(Bg + (long)rr * K + k0, Bs + rr * 32);
    }
    __syncthreads();
    const int ko = (lane >> 4) * 8;
    short8 af[4], bq[4];
#pragma unroll
    for (int i = 0; i < 4; ++i) {
      af[i] = *(const short8*)(As + (wm + i * 16 + (lane & 15)) * 32 + ko);
      bq[i] = *(const short8*)(Bs + (wn + i * 16 + (lane & 15)) * 32 + ko);
    }
#pragma unroll
    for (int i = 0; i < 4; ++i)
#pragma unroll
      for (int j = 0; j < 4; ++j)
        mfma16(acc[i][j], af[i], bq[j]);
    __syncthreads();
  }
  const int cr = (lane >> 4) * 4, cc = lane & 15;
#pragma unroll
  for (int i = 0; i < 4; ++i)
#pragma unroll
    for (int j = 0; j < 4; ++j)
#pragma unroll
      for (int r = 0; r < 4; ++r) {
        long m = m0 + wm + i * 16 + cr + r;
        long n = n0 + wn + j * 16 + cc;
        float val = acc[i][j][r];
        if (EPI == 0) {
          ((bf16*)Cv)[m * N + n] = __float2bfloat16(val);
        } else if (EPI == 1) {
          long z = (m >> 11) * 4 + (n >> 7);
          ((bf16*)Cv)[z * (HD * (long)TSEQ) + (n & 127) * (long)TSEQ + (m & 2047)] =
              __float2bfloat16(val);
        } else {
          ((float*)Cv)[m * N + n] = val;
        }
      }
}

// ---------------- flash attention fwd, full (non-causal) ----------------
// grid: (T/128, 16 heads, B). 8 waves x 16 q-rows = 128 q-rows/block.
// KV tile = 64. LDS 53KB -> 2 blocks/CU (16 waves). Reg-prefetch next tile.
__global__ __launch_bounds__(512, 4) void attn_fwd(const bf16* __restrict__ Qp,
                                                   const bf16* __restrict__ Kp,
                                                   const bf16* __restrict__ Vt,
                                                   bf16* __restrict__ AO) {
  __shared__ bf16 Ks[64 * 136];    // [s][d]
  __shared__ bf16 Vts[128 * 72];   // [d][s]
  __shared__ bf16 Plds[8][16 * 72];
  const int tid = threadIdx.x;
  const int lane = tid & 63, wid = tid >> 6;
  const int h = blockIdx.y, b = blockIdx.z;
  const int kv = h >> 2;
  const int t0 = blockIdx.x * 128;
  const int lr = lane & 15, lg = lane >> 4;

  short8 aq[4];
  {
    const bf16* qrow =
        Qp + ((long)(b * TSEQ + t0 + wid * 16 + lr)) * DIMC + h * HD + lg * 8;
#pragma unroll
    for (int c = 0; c < 4; ++c) aq[c] = *(const short8*)(qrow + c * 32);
  }
  f32x4 o[8] = {};
  float mrun[4], lrun[4];
#pragma unroll
  for (int r = 0; r < 4; ++r) { mrun[r] = -1e30f; lrun[r] = 0.f; }

  const bf16* Kg = Kp + (long)b * TSEQ * KVD + kv * HD;
  const bf16* Vg = Vt + ((long)(b * KVH + kv)) * HD * TSEQ;

  // staging decomposition across 512 threads: each thread owns 16 contiguous
  // K elems (row tid>>3, cols (tid&7)*16 + p*8) and 16 contiguous V elems
  // (row tid>>2, cols (tid&3)*16 + p*8).
  const int krow = tid >> 3, kc0 = (tid & 7) * 16;
  const int vrow = tid >> 2, vc0 = (tid & 3) * 16;
  short8 kreg[2], vreg[2];
#pragma unroll
  for (int p = 0; p < 2; ++p) {
    kreg[p] = *(const short8*)(Kg + (long)krow * KVD + kc0 + p * 8);
    vreg[p] = *(const short8*)(Vg + (long)vrow * TSEQ + vc0 + p * 8);
  }

  for (int s0 = 0; s0 < TSEQ; s0 += 64) {
    __syncthreads();  // prev-tile LDS reads done
#pragma unroll
    for (int p = 0; p < 2; ++p) {
      *(short8*)(Ks + krow * 136 + kc0 + p * 8) = kreg[p];
      *(short8*)(Vts + vrow * 72 + vc0 + p * 8) = vreg[p];
    }
    __syncthreads();
    if (s0 + 64 < TSEQ) {  // prefetch next tile; completes under compute
#pragma unroll
      for (int p = 0; p < 2; ++p) {
        kreg[p] = *(const short8*)(Kg + (long)(s0 + 64 + krow) * KVD + kc0 + p * 8);
        vreg[p] = *(const short8*)(Vg + (long)vrow * TSEQ + s0 + 64 + vc0 + p * 8);
      }
    }

    // S = Q K^T (log2-scaled; scale folded into Wq)
    f32x4 sacc[4] = {};
#pragma unroll
    for (int sf = 0; sf < 4; ++sf)
#pragma unroll
      for (int c = 0; c < 4; ++c) {
        short8 kf = *(const short8*)(Ks + (sf * 16 + lr) * 136 + c * 32 + lg * 8);
        mfma16(sacc[sf], aq[c], kf);
      }

    // online softmax (base-2); lane holds rows lg*4+r, col sf*16+lr
    float tmax[4];
#pragma unroll
    for (int r = 0; r < 4; ++r)
      tmax[r] = fmaxf(fmaxf(sacc[0][r], sacc[1][r]),
                      fmaxf(sacc[2][r], sacc[3][r]));
#pragma unroll
    for (int r = 0; r < 4; ++r)
#pragma unroll
      for (int mm = 1; mm < 16; mm <<= 1)
        tmax[r] = fmaxf(tmax[r], __shfl_xor(tmax[r], mm));
    int need = 0;
#pragma unroll
    for (int r = 0; r < 4; ++r) need |= (tmax[r] > mrun[r]);
    if (__any(need)) {  // defer-max: skip rescale when max didn't grow
#pragma unroll
      for (int r = 0; r < 4; ++r) {
        float mnew = fmaxf(mrun[r], tmax[r]);
        float fac = exp2f(mrun[r] - mnew);
        mrun[r] = mnew;
        lrun[r] *= fac;
#pragma unroll
        for (int df = 0; df < 8; ++df) o[df][r] *= fac;
      }
    }
    float psum[4] = {0.f, 0.f, 0.f, 0.f};
    bf16* Pw = Plds[wid];
#pragma unroll
    for (int sf = 0; sf < 4; ++sf)
#pragma unroll
      for (int r = 0; r < 4; ++r) {
        float p = exp2f(sacc[sf][r] - mrun[r]);
        psum[r] += p;
        Pw[(lg * 4 + r) * 72 + sf * 16 + lr] = __float2bfloat16(p);
      }
#pragma unroll
    for (int r = 0; r < 4; ++r) {
#pragma unroll
      for (int mm = 1; mm < 16; mm <<= 1)
        psum[r] += __shfl_xor(psum[r], mm);
      lrun[r] += psum[r];
    }

    // O += P V
#pragma unroll
    for (int c2 = 0; c2 < 2; ++c2) {
      short8 pa = *(const short8*)(Pw + lr * 72 + c2 * 32 + lg * 8);
#pragma unroll
      for (int df = 0; df < 8; ++df) {
        short8 vf = *(const short8*)(Vts + (df * 16 + lr) * 72 + c2 * 32 + lg * 8);
        mfma16(o[df], pa, vf);
      }
    }
  }

  bf16* orow =
      AO + ((long)(b * TSEQ + t0 + wid * 16 + lg * 4)) * DIMC + h * HD + lr;
#pragma unroll
  for (int df = 0; df < 8; ++df)
#pragma unroll
    for (int r = 0; r < 4; ++r) {
      float v = o[df][r] / lrun[r];
      orow[(long)r * DIMC + df * 16] = __float2bfloat16(v);
    }
}

extern "C" void kernel_launch(void* const* d_in, const int* in_sizes, int n_in,
                              void* d_out, int out_size, void* d_ws, size_t ws_size,
                              hipStream_t stream) {
  const float* x  = (const float*)d_in[0];
  const float* Wq = (const float*)d_in[1];
  const float* Wk = (const float*)d_in[2];
  const float* Wv = (const float*)d_in[3];
  const float* Wo = (const float*)d_in[4];
  float* out = (float*)d_out;
  bf16* ws = (bf16*)d_ws;

  bf16* xb  = ws;                 // [4096][2048] x (bf16); later reused as ao
  bf16* WT1 = xb + 8388608;       // [2048][2048] WqT, then WoT
  bf16* WT2 = WT1 + 4194304;      // [512][2048]  WkT, then WvT
  bf16* qp  = WT2 + 1048576;      // [4096][2048]
  bf16* kp  = qp + 8388608;       // [4096][512]
  bf16* vT  = kp + 2097152;       // [8][128][2048]

  f2b<<<8192, 256, 0, stream>>>(x, xb, 2097152);
  transpose_w_f2b<<<dim3(32, 32), 256, 0, stream>>>(Wq, WT1, 2048, QSCALE);
  transpose_w_f2b<<<dim3(8, 32), 256, 0, stream>>>(Wk, WT2, 512, 1.0f);

  gemm_bt<0><<<dim3(16, 32), 256, 0, stream>>>(xb, WT1, qp, 4096, 2048, 2048);
  gemm_bt<0><<<dim3(4, 32), 256, 0, stream>>>(xb, WT2, kp, 4096, 512, 2048);

  transpose_w_f2b<<<dim3(8, 32), 256, 0, stream>>>(Wv, WT2, 512, 1.0f);
  gemm_bt<1><<<dim3(4, 32), 256, 0, stream>>>(xb, WT2, vT, 4096, 512, 2048);

  transpose_w_f2b<<<dim3(32, 32), 256, 0, stream>>>(Wo, WT1, 2048, 1.0f);

  bf16* ao = xb;  // x dead after V gemm
  attn_fwd<<<dim3(16, 16, 2), 512, 0, stream>>>(qp, kp, vT, ao);

  gemm_bt<2><<<dim3(16, 32), 256, 0, stream>>>(ao, WT1, out, 4096, 2048, 2048);
}